// Round 8
// baseline (2704.622 us; speedup 1.0000x reference)
//
#include <hip/hip_runtime.h>
#include <stdint.h>

// V=32000, E=256, H=512, S=128, B=32, T=32

using short8 = __attribute__((ext_vector_type(8))) short;
using f32x4  = __attribute__((ext_vector_type(4))) float;
typedef _Float16 half2v __attribute__((ext_vector_type(2)));

__device__ __forceinline__ short f2bf(float x){
  unsigned u = __float_as_uint(x);
  unsigned r = (u + 0x7fffu + ((u >> 16) & 1u)) >> 16;
  return (short)(unsigned short)r;
}
__device__ __forceinline__ float bf2f_lo(unsigned u){ return __uint_as_float(u << 16); }
__device__ __forceinline__ float bf2f_hi(unsigned u){ return __uint_as_float(u & 0xffff0000u); }
__device__ __forceinline__ float sigmf(float x){ return 1.0f/(1.0f + __expf(-x)); }
__device__ __forceinline__ float fast_tanh(float x){
  const float e = __expf(2.0f*x);
  return 1.0f - 2.0f/(e + 1.0f);
}
__device__ __forceinline__ unsigned pack_h2(float a, float b){
  unsigned short ha = __builtin_bit_cast(unsigned short, (_Float16)a);
  unsigned short hb = __builtin_bit_cast(unsigned short, (_Float16)b);
  return (unsigned)ha | ((unsigned)hb << 16);
}
__device__ __forceinline__ float h2lo(unsigned u){ return (float)__builtin_bit_cast(half2v,u)[0]; }
__device__ __forceinline__ float h2hi(unsigned u){ return (float)__builtin_bit_cast(half2v,u)[1]; }
__device__ __forceinline__ float dot2u(unsigned x, unsigned w, float c){
#if __has_builtin(__builtin_amdgcn_fdot2)
  return __builtin_amdgcn_fdot2(__builtin_bit_cast(half2v,x), __builtin_bit_cast(half2v,w), c, false);
#else
  half2v hx = __builtin_bit_cast(half2v,x), hw = __builtin_bit_cast(half2v,w);
  c = fmaf((float)hx[0], (float)hw[0], c);
  c = fmaf((float)hx[1], (float)hw[1], c);
  return c;
#endif
}

// ---------------------------------------------------------------------------
// coherent (LLC) accessors
__device__ __forceinline__ float4 load_coh_f4(const float* p){
  float4 v;
  asm volatile("global_load_dwordx4 %0, %1, off sc0 sc1\n\ts_waitcnt vmcnt(0)"
               : "=&v"(v) : "v"(p) : "memory");
  return v;
}
__device__ __forceinline__ void store_coh_u32(unsigned* p, unsigned v){
  asm volatile("global_store_dword %0, %1, off sc0 sc1" :: "v"(p), "v"(v) : "memory");
}

// spread flags: one flag per 64B line (16 uints). wave0: lane l polls flag l.
__device__ __forceinline__ void wait_spread(const unsigned* base, int n, unsigned target){
  if (threadIdx.x < 64){
    const bool mine = (int)threadIdx.x < n;
    const unsigned* p = base + (threadIdx.x << 4);
    for(;;){
      unsigned v = target;
      if (mine)
        asm volatile("global_load_dword %0, %1, off sc0 sc1\n\ts_waitcnt vmcnt(0)"
                     : "=&v"(v) : "v"(p) : "memory");
      if (__all(v >= target)) break;
    }
  }
  __syncthreads();
}
__device__ __forceinline__ void set_flag_sp(unsigned* slot, unsigned val){
  asm volatile("s_waitcnt vmcnt(0)" ::: "memory");
  __syncthreads();
  if (threadIdx.x == 0) store_coh_u32(slot, val);
}

// stage 8 rows x 256 uints (f16 pairs) from [32][256] u array (rows bg*8..+8)
// into LDS rows of stride 260. Exactly 2 batched 16B loads per thread.
__device__ __forceinline__ void stage8u(const unsigned* src, int bg, unsigned* lds){
  const unsigned* s0 = src + (size_t)bg*2048;
  const int f0 = threadIdx.x, f1 = f0 + 256;     // uint4 indices
  uint4 a, b;
  asm volatile(
    "global_load_dwordx4 %0, %2, off sc0 sc1\n\t"
    "global_load_dwordx4 %1, %3, off sc0 sc1\n\t"
    "s_waitcnt vmcnt(0)"
    : "=&v"(a), "=&v"(b)
    : "v"(s0 + (f0<<2)), "v"(s0 + (f1<<2))
    : "memory");
  { const int row = f0>>6, cu = (f0&63)<<2; *(uint4*)&lds[row*260+cu] = a; }
  { const int row = f1>>6, cu = (f1&63)<<2; *(uint4*)&lds[row*260+cu] = b; }
}

// 512-elem f16 dot: x (LDS row, 256 uints) . w (global f16 row)
__device__ __forceinline__ float dot512(const unsigned* xrow, const unsigned* w){
  float a = 0.f;
  #pragma unroll 4
  for (int it = 0; it < 16; ++it){
    uint4 x0 = *(const uint4*)(xrow + it*16);
    uint4 x1 = *(const uint4*)(xrow + it*16 + 4);
    uint4 x2 = *(const uint4*)(xrow + it*16 + 8);
    uint4 x3 = *(const uint4*)(xrow + it*16 + 12);
    uint4 w0 = *(const uint4*)(w + it*16);
    uint4 w1 = *(const uint4*)(w + it*16 + 4);
    uint4 w2 = *(const uint4*)(w + it*16 + 8);
    uint4 w3 = *(const uint4*)(w + it*16 + 12);
    a = dot2u(x0.x,w0.x,a); a = dot2u(x0.y,w0.y,a); a = dot2u(x0.z,w0.z,a); a = dot2u(x0.w,w0.w,a);
    a = dot2u(x1.x,w1.x,a); a = dot2u(x1.y,w1.y,a); a = dot2u(x1.z,w1.z,a); a = dot2u(x1.w,w1.w,a);
    a = dot2u(x2.x,w2.x,a); a = dot2u(x2.y,w2.y,a); a = dot2u(x2.z,w2.z,a); a = dot2u(x2.w,w2.w,a);
    a = dot2u(x3.x,w3.x,a); a = dot2u(x3.y,w3.y,a); a = dot2u(x3.z,w3.z,a); a = dot2u(x3.w,w3.w,a);
  }
  return a;
}

// two arbitrary weight rows vs same LDS x (shared x loads)
__device__ __forceinline__ float2 dot2rows(const unsigned* xrow, const unsigned* wA, const unsigned* wB){
  float a = 0.f, b = 0.f;
  #pragma unroll 8
  for (int it = 0; it < 32; ++it){
    uint4 x0 = *(const uint4*)(xrow + it*8);
    uint4 x1 = *(const uint4*)(xrow + it*8 + 4);
    uint4 a0 = *(const uint4*)(wA + it*8);
    uint4 a1 = *(const uint4*)(wA + it*8 + 4);
    uint4 b0 = *(const uint4*)(wB + it*8);
    uint4 b1 = *(const uint4*)(wB + it*8 + 4);
    a = dot2u(x0.x,a0.x,a); a = dot2u(x0.y,a0.y,a); a = dot2u(x0.z,a0.z,a); a = dot2u(x0.w,a0.w,a);
    a = dot2u(x1.x,a1.x,a); a = dot2u(x1.y,a1.y,a); a = dot2u(x1.z,a1.z,a); a = dot2u(x1.w,a1.w,a);
    b = dot2u(x0.x,b0.x,b); b = dot2u(x0.y,b0.y,b); b = dot2u(x0.z,b0.z,b); b = dot2u(x0.w,b0.w,b);
    b = dot2u(x1.x,b1.x,b); b = dot2u(x1.y,b1.y,b); b = dot2u(x1.z,b1.z,b); b = dot2u(x1.w,b1.w,b);
  }
  return make_float2(a, b);
}

// ---------------------------------------------------------------------------
__global__ void k_zero(float* __restrict__ p, int n){
  int i = blockIdx.x*256 + threadIdx.x;
  const int stride = gridDim.x*256;
  for (; i < n; i += stride) p[i] = 0.f;
}

__global__ __launch_bounds__(256) void k_cvt_f16(const float* __restrict__ s, unsigned short* __restrict__ d, int n){
  int i = blockIdx.x*256 + threadIdx.x;
  const int stride = gridDim.x*256;
  for (; i < n; i += stride) d[i] = __builtin_bit_cast(unsigned short, (_Float16)s[i]);
}
__global__ __launch_bounds__(256) void k_cvt_f16_str(const float* __restrict__ s, int lds_, unsigned short* __restrict__ d, int n){
  int i = blockIdx.x*256 + threadIdx.x;
  const int stride = gridDim.x*256;
  for (; i < n; i += stride){
    const int row = i >> 9, c = i & 511;
    d[i] = __builtin_bit_cast(unsigned short, (_Float16)s[(size_t)row*lds_ + c]);
  }
}

// ---------------------------------------------------------------------------
__global__ __launch_bounds__(256) void k_gather(
    const int* __restrict__ src, const int* __restrict__ trg,
    const float* __restrict__ embed,
    short* __restrict__ emb_src_bf, short* __restrict__ emb_trg_bf)
{
  const int row = blockIdx.x, tid = threadIdx.x;
  if (row < 4096){
    const int tok = src[row];
    emb_src_bf[(size_t)row*256 + tid] = f2bf(embed[(size_t)tok*256 + tid]);
  } else {
    const int r = row - 4096;
    short v = 0;
    if (r < 992){ const int tok = trg[r]; v = f2bf(embed[(size_t)tok*256 + tid]); }
    emb_trg_bf[(size_t)r*256 + tid] = v;
  }
}

// ---------------------------------------------------------------------------
// MFMA GEMM: A_bf16 @ W_f32^T + biases. tmode: C_T[t][col][b]; Cbf: bf16 output
__global__ __launch_bounds__(256) void k_gemm_aw(
    const short* __restrict__ A, int lda,
    const float* __restrict__ W, int ldw,
    float* __restrict__ C, int ldc,
    const float* __restrict__ bias0, const float* __restrict__ bias1,
    int Mvalid, int K, int tmode, short* __restrict__ Cbf)
{
  __shared__ __align__(16) short As[128*32];
  __shared__ __align__(16) short Bs[128*32];
  const int tid = threadIdx.x;
  const int bm = blockIdx.x, bn = blockIdx.y;
  const int w  = tid >> 6,  l  = tid & 63;
  const int wm = w >> 1,    wn = w & 1;
  const int lr = l & 15,    lk = l >> 4;

  const int r0 = tid >> 2;
  const int s0 = (tid & 3) << 3;
  const int r1 = r0 + 64;

  const short* a0 = A + (size_t)(bm*128 + r0)*lda + s0;
  const short* a1 = A + (size_t)(bm*128 + r1)*lda + s0;
  const float* w0 = W + (size_t)(bn*128 + r0)*ldw + s0;
  const float* w1 = W + (size_t)(bn*128 + r1)*ldw + s0;

  const f32x4 zero4 = {0.f,0.f,0.f,0.f};
  f32x4 acc[4][4];
  #pragma unroll
  for (int mi=0;mi<4;mi++){
    #pragma unroll
    for (int ni=0;ni<4;ni++) acc[mi][ni] = zero4;
  }

  for (int k0 = 0; k0 < K; k0 += 32){
    short8 va0 = *(const short8*)(a0 + k0);
    short8 va1 = *(const short8*)(a1 + k0);
    float4 f00 = *(const float4*)(w0 + k0);
    float4 f01 = *(const float4*)(w0 + k0 + 4);
    float4 f10 = *(const float4*)(w1 + k0);
    float4 f11 = *(const float4*)(w1 + k0 + 4);
    short8 vb0, vb1;
    vb0[0]=f2bf(f00.x); vb0[1]=f2bf(f00.y); vb0[2]=f2bf(f00.z); vb0[3]=f2bf(f00.w);
    vb0[4]=f2bf(f01.x); vb0[5]=f2bf(f01.y); vb0[6]=f2bf(f01.z); vb0[7]=f2bf(f01.w);
    vb1[0]=f2bf(f10.x); vb1[1]=f2bf(f10.y); vb1[2]=f2bf(f10.z); vb1[3]=f2bf(f10.w);
    vb1[4]=f2bf(f11.x); vb1[5]=f2bf(f11.y); vb1[6]=f2bf(f11.z); vb1[7]=f2bf(f11.w);

    __syncthreads();
    *((short8*)As + tid)       = va0;
    *((short8*)As + tid + 256) = va1;
    *((short8*)Bs + tid)       = vb0;
    *((short8*)Bs + tid + 256) = vb1;
    __syncthreads();

    short8 af[4], bfr[4];
    #pragma unroll
    for (int mi=0;mi<4;mi++) af[mi]  = *(const short8*)&As[(wm*64 + mi*16 + lr)*32 + (lk<<3)];
    #pragma unroll
    for (int ni=0;ni<4;ni++) bfr[ni] = *(const short8*)&Bs[(wn*64 + ni*16 + lr)*32 + (lk<<3)];
    #pragma unroll
    for (int mi=0;mi<4;mi++){
      #pragma unroll
      for (int ni=0;ni<4;ni++)
        acc[mi][ni] = __builtin_amdgcn_mfma_f32_16x16x32_bf16(af[mi], bfr[ni], acc[mi][ni], 0,0,0);
    }
  }

  #pragma unroll
  for (int mi=0;mi<4;mi++){
    const int rb = bm*128 + wm*64 + mi*16 + (lk<<2);
    #pragma unroll
    for (int ni=0;ni<4;ni++){
      const int col = bn*128 + wn*64 + ni*16 + lr;
      float bv = 0.f;
      if (bias0) bv += bias0[col];
      if (bias1) bv += bias1[col];
      #pragma unroll
      for (int rr=0;rr<4;rr++){
        const int row = rb + rr;
        if (row < Mvalid){
          const float vv = acc[mi][ni][rr] + bv;
          if (Cbf)        Cbf[(size_t)row*ldc + col] = f2bf(vv);
          else if (tmode) C[(size_t)(row>>5)*65536 + (size_t)col*32 + (row&31)] = vv;
          else            C[(size_t)row*ldc + col] = vv;
        }
      }
    }
  }
}

// ---------------------------------------------------------------------------
// persistent bidirectional encoder, 256 blocks. h handoff = f16 pairs.
// x=bid&7, m=bid>>3: dir=m&1, bg=(m>>1)&3, jb=x*4+(m>>3) in 0..31.
__global__ __launch_bounds__(256,1) void k_enc_persist(
    const float* __restrict__ pre_f, const float* __restrict__ pre_b,  // [128][2048][32]
    const unsigned short* __restrict__ WhF, const unsigned short* __restrict__ WhB, // f16 [2048][512]
    unsigned* __restrict__ f_outs, unsigned* __restrict__ b_outs,      // [128][32][256] f16 pairs
    float* __restrict__ c_f_out, float* __restrict__ c_b_out,
    unsigned* __restrict__ eflag)                                      // [8][32][16]
{
  __shared__ __align__(16) unsigned x_lds[8*260];
  __shared__ float zbuf[64*8];
  const int bid = blockIdx.x, tid = threadIdx.x;
  const int x = bid & 7, m = bid >> 3;
  const int dir = m & 1, bg = (m >> 1) & 3, q = m >> 3;
  const int jb = x*4 + q;
  const float* pre = dir ? pre_b : pre_f;
  const unsigned* Wh = (const unsigned*)(dir ? WhB : WhF);
  unsigned* outs = dir ? b_outs : f_outs;
  float* c_out = dir ? c_b_out : c_f_out;
  unsigned* flags = eflag + (size_t)(dir*4 + bg)*512;

  const int bb = tid & 7, rr = tid >> 3;
  const int g = rr >> 3, op = rr & 7;
  const unsigned* wA = Wh + (size_t)(g*512 + jb*16 + 2*op)*256;
  const unsigned* wB = wA + 256;

  const int fo = tid & 15, fb = tid >> 4;       // finish (tid<128)
  const int b_out = bg*8 + fb, k_out = jb*16 + fo;
  float c_reg = 0.f;

  for (int t = 0; t < 128; ++t){
    // prefetch pre[t] (plain loads; hides under wait+stage)
    float pz[4];
    if (tid < 128){
      const int tt = dir ? (127 - t) : t;
      const float* pt = pre + (size_t)tt*65536;
      #pragma unroll
      for (int gg = 0; gg < 4; ++gg)
        pz[gg] = pt[(size_t)(gg*512 + k_out)*32 + b_out];
    }
    if (t){
      wait_spread(flags, 32, (unsigned)t);
      stage8u(outs + (size_t)(t-1)*8192, bg, x_lds);
    } else {
      for (int i = tid; i < 8*260; i += 256) x_lds[i] = 0;
    }
    __syncthreads();

    const float2 d = dot2rows(x_lds + bb*260, wA, wB);
    zbuf[(g*16 + 2*op)*8 + bb]   = d.x;
    zbuf[(g*16 + 2*op+1)*8 + bb] = d.y;
    __syncthreads();

    if (tid < 128){
      float z[4];
      #pragma unroll
      for (int gg = 0; gg < 4; ++gg)
        z[gg] = pz[gg] + zbuf[(gg*16 + fo)*8 + fb];
      const float cn = sigmf(z[1])*c_reg + sigmf(z[0])*fast_tanh(z[2]);
      c_reg = cn;
      const float hn = sigmf(z[3])*fast_tanh(cn);
      const unsigned pu = pack_h2(hn, __shfl_xor(hn, 1));
      if (!(tid & 1))
        store_coh_u32(outs + (size_t)t*8192 + (size_t)b_out*256 + (k_out>>1), pu);
    }
    set_flag_sp(flags + jb*16, (unsigned)(t+1));
  }
  if (tid < 128) c_out[b_out*512 + k_out] = c_reg;
}

// ---------------------------------------------------------------------------
// sum fwd/bwd f16-pair outs -> bf16 pairs
__global__ __launch_bounds__(256) void k_sum_enc(
    const unsigned* __restrict__ f_o, const unsigned* __restrict__ b_o,
    unsigned* __restrict__ enc_sum_bf_u)
{
  const int i = blockIdx.x*256 + threadIdx.x;       // < 1048576
  const int s = i >> 13, rem = i & 8191;
  const unsigned a = f_o[i], b = b_o[(size_t)(127 - s)*8192 + rem];
  const float lo = h2lo(a) + h2lo(b);
  const float hi = h2hi(a) + h2hi(b);
  enc_sum_bf_u[i] = (unsigned)(unsigned short)f2bf(lo) | ((unsigned)(unsigned short)f2bf(hi) << 16);
}

// ---------------------------------------------------------------------------
// persistent decoder, 256 blocks, 3 flag-synced phases/step.
// jb = (bid&7)*8 + ((bid>>3)>>2) in 0..63, bg = (bid>>3)&3; attn: blocks 0..31.
// A: attn blocks compute qs(own batch, from LDS h1) + scores + softmax + ctx.
// B: zh1 (all, x1s), cell0: h0 = gates(demb + Wih0c.ctx + zh0)
// C: cell1: h1 = gates(bias1 + Wih1.h0 + zh1); zh0' = Whh0.h0
__global__ __launch_bounds__(256,1) void k_dec_persist(
    const float* __restrict__ demb,               // [32][2048][32] (+bih0+bhh0)
    const unsigned short* __restrict__ Wih0h,
    const unsigned short* __restrict__ Whh0h,
    const unsigned short* __restrict__ Wih1h,
    const unsigned short* __restrict__ Whh1h,
    const float* __restrict__ bih1, const float* __restrict__ bhh1,
    const unsigned short* __restrict__ wqh,       // f16 [512][512]
    const float* __restrict__ attnV,
    const short* __restrict__ enc_proj_bf,        // [4096][512] (+attn_b)
    const short* __restrict__ enc_sum_bf,         // [4096][512]
    const unsigned* __restrict__ h0i, const unsigned* __restrict__ h1i, // [32][256] f16
    const float* __restrict__ c0_init, const float* __restrict__ c1_init,
    unsigned* __restrict__ h0buf, unsigned* __restrict__ h1buf,  // [2][32][256]
    unsigned* __restrict__ ctxb,                                 // [32][256]
    short* __restrict__ h1ctx,                                   // [31][32][1024] bf16
    unsigned* __restrict__ flagC, unsigned* __restrict__ flagA)
{
  __shared__ __align__(16) unsigned x0s[8*260];
  __shared__ __align__(16) unsigned x1s[8*260];
  __shared__ float zfin[32*9];
  __shared__ __align__(16) float q_s[512], v_s[512];
  __shared__ float part[256], aw[128], red[128];

  const int bid = blockIdx.x, tid = threadIdx.x;
  const int jb = (bid & 7)*8 + ((bid >> 3) >> 2);
  const int bg = (bid >> 3) & 3;
  unsigned* grpC = flagC + bg*1024;
  unsigned* myC  = grpC + jb*16;
  unsigned* grpA = flagA + bg*128;

  const int b = tid & 7, r = tid >> 3;
  const int g = r >> 3, o = r & 7;
  const int j_row = g*512 + jb*8 + o;

  const int fo = tid & 7, fb = tid >> 3;        // finish (tid<64)
  const int b_out = bg*8 + fb, k_out = jb*8 + fo;

  const unsigned* Wh0row = (const unsigned*)Whh0h + (size_t)j_row*256;
  const unsigned* Wh1row = (const unsigned*)Whh1h + (size_t)j_row*256;
  const unsigned* Wi0row = (const unsigned*)Wih0h + (size_t)j_row*256;
  const unsigned* Wi1row = (const unsigned*)Wih1h + (size_t)j_row*256;
  const unsigned* WQ     = (const unsigned*)wqh;

  float c0_reg = 0.f, c1_reg = 0.f, bias1g[4];
  if (tid < 64){
    c0_reg = c0_init[b_out*512 + k_out];
    c1_reg = c1_init[b_out*512 + k_out];
    #pragma unroll
    for (int gg=0; gg<4; ++gg) bias1g[gg] = bih1[gg*512 + k_out] + bhh1[gg*512 + k_out];
  }
  if (bid < 32 && tid < 128) ((float4*)v_s)[tid] = ((const float4*)attnV)[tid];

  float zh0 = 0.f;

  for (int t = 0; t < 31; ++t){
    const float demb_v = demb[(size_t)t*65536 + (size_t)j_row*32 + bg*8 + b];

    // ---------------- Phase A ----------------
    if (t){
      wait_spread(grpC, 64, (unsigned)(2*t));
      stage8u(h1buf + (size_t)(t&1)*8192, bg, x1s);
    } else {
      stage8u(h1i, bg, x1s);
      stage8u(h0i, bg, x0s);
    }
    __syncthreads();
    if (t == 0) zh0 = dot512(x0s + b*260, Wh0row);
    if (bid < 32){
      const int ab = bid;
      {
        const float2 qq = dot2rows(x1s + (ab&7)*260,
                                   WQ + (size_t)tid*256, WQ + (size_t)(tid+256)*256);
        q_s[tid] = qq.x; q_s[tid+256] = qq.y;
      }
      __syncthreads();
      {
        const int s = tid >> 1, half = tid & 1;
        const unsigned* ep = (const unsigned*)(enc_proj_bf + ((size_t)(s*32 + ab))*512 + (half << 8));
        const float* qh = q_s + (half << 8);
        const float* vh = v_s + (half << 8);
        float p = 0.f;
        for (int kk = 0; kk < 128; kk += 4){
          uint4 e = *(const uint4*)(ep + kk);
          const int k2 = kk << 1;
          p += fast_tanh(qh[k2+0] + bf2f_lo(e.x)) * vh[k2+0];
          p += fast_tanh(qh[k2+1] + bf2f_hi(e.x)) * vh[k2+1];
          p += fast_tanh(qh[k2+2] + bf2f_lo(e.y)) * vh[k2+2];
          p += fast_tanh(qh[k2+3] + bf2f_hi(e.y)) * vh[k2+3];
          p += fast_tanh(qh[k2+4] + bf2f_lo(e.z)) * vh[k2+4];
          p += fast_tanh(qh[k2+5] + bf2f_hi(e.z)) * vh[k2+5];
          p += fast_tanh(qh[k2+6] + bf2f_lo(e.w)) * vh[k2+6];
          p += fast_tanh(qh[k2+7] + bf2f_hi(e.w)) * vh[k2+7];
        }
        part[tid] = p;
      }
      __syncthreads();
      if (tid < 128){ const float sc = part[2*tid] + part[2*tid+1]; aw[tid] = sc; red[tid] = sc; }
      __syncthreads();
      for (int off = 64; off > 0; off >>= 1){
        if (tid < off) red[tid] = fmaxf(red[tid], red[tid+off]);
        __syncthreads();
      }
      const float mx = red[0];
      __syncthreads();
      if (tid < 128){ const float e = __expf(aw[tid] - mx); aw[tid] = e; red[tid] = e; }
      __syncthreads();
      for (int off = 64; off > 0; off >>= 1){
        if (tid < off) red[tid] += red[tid+off];
        __syncthreads();
      }
      const float inv = 1.0f / red[0];
      if (tid < 128) aw[tid] *= inv;
      __syncthreads();
      {
        const int cc = tid << 1;
        float x0 = 0.f, x1 = 0.f;
        for (int s2 = 0; s2 < 128; ++s2){
          const unsigned u = *(const unsigned*)(enc_sum_bf + ((size_t)(s2*32 + ab))*512 + cc);
          const float a = aw[s2];
          x0 = fmaf(a, bf2f_lo(u), x0);
          x1 = fmaf(a, bf2f_hi(u), x1);
        }
        store_coh_u32(ctxb + (size_t)ab*256 + tid, pack_h2(x0, x1));
        h1ctx[(size_t)t*32768 + ab*1024 + 512 + cc]     = f2bf(x0);
        h1ctx[(size_t)t*32768 + ab*1024 + 512 + cc + 1] = f2bf(x1);
      }
      set_flag_sp(grpA + (bid&7)*16, (unsigned)(t+1));
    }

    // ---------------- Phase B ----------------
    wait_spread(grpA, 8, (unsigned)(t+1));
    const float zh1 = dot512(x1s + b*260, Wh1row);     // x1s still h1[t-1]
    stage8u(ctxb, bg, x0s);
    __syncthreads();
    zfin[r*9 + b] = demb_v + dot512(x0s + b*260, Wi0row) + zh0;
    __syncthreads();
    if (tid < 64){
      float z[4];
      #pragma unroll
      for (int gg=0; gg<4; ++gg) z[gg] = zfin[(gg*8 + fo)*9 + fb];
      const float cn = sigmf(z[1])*c0_reg + sigmf(z[0])*fast_tanh(z[2]);
      c0_reg = cn;
      const float hn = sigmf(z[3])*fast_tanh(cn);
      const unsigned pu = pack_h2(hn, __shfl_xor(hn, 1));
      if (!(tid & 1))
        store_coh_u32(h0buf + (size_t)((t+1)&1)*8192 + (size_t)b_out*256 + (k_out>>1), pu);
    }
    set_flag_sp(myC, (unsigned)(2*t+1));

    // ---------------- Phase C ----------------
    wait_spread(grpC, 64, (unsigned)(2*t+1));
    stage8u(h0buf + (size_t)((t+1)&1)*8192, bg, x0s);
    __syncthreads();
    {
      const float2 d = dot2rows(x0s + b*260, Wi1row, Wh0row);
      zfin[r*9 + b] = d.x + zh1;
      zh0 = d.y;                                       // for step t+1
    }
    __syncthreads();
    if (tid < 64){
      float z[4];
      #pragma unroll
      for (int gg=0; gg<4; ++gg) z[gg] = bias1g[gg] + zfin[(gg*8 + fo)*9 + fb];
      const float cn = sigmf(z[1])*c1_reg + sigmf(z[0])*fast_tanh(z[2]);
      c1_reg = cn;
      const float hn = sigmf(z[3])*fast_tanh(cn);
      const unsigned pu = pack_h2(hn, __shfl_xor(hn, 1));
      if (!(tid & 1))
        store_coh_u32(h1buf + (size_t)((t+1)&1)*8192 + (size_t)b_out*256 + (k_out>>1), pu);
      h1ctx[(size_t)t*32768 + (size_t)b_out*1024 + k_out] = f2bf(hn);
    }
    set_flag_sp(myC, (unsigned)(2*t+2));
  }
}

// ---------------------------------------------------------------------------
// log_softmax without max pass (|logits| << 88): lse = log(sum exp z)
__global__ __launch_bounds__(256) void k_logsm(float* __restrict__ out){
  float* row = out + (size_t)blockIdx.x * 32000;
  const int tid = threadIdx.x;
  __shared__ float red[256];
  float s = 0.f;
  for (int i = tid; i < 8000; i += 256){
    const float4 v = ((const float4*)row)[i];
    s += __expf(v.x) + __expf(v.y) + __expf(v.z) + __expf(v.w);
  }
  red[tid] = s; __syncthreads();
  for (int off = 128; off > 0; off >>= 1){
    if (tid < off) red[tid] += red[tid+off];
    __syncthreads();
  }
  const float lse = __logf(red[0]);
  for (int i = tid; i < 8000; i += 256){
    float4 v = ((const float4*)row)[i];
    v.x -= lse; v.y -= lse; v.z -= lse; v.w -= lse;
    ((float4*)row)[i] = v;
  }
}

// ---------------------------------------------------------------------------
extern "C" void kernel_launch(void* const* d_in, const int* in_sizes, int n_in,
                              void* d_out, int out_size, void* d_ws, size_t ws_size,
                              hipStream_t stream)
{
  (void)in_sizes; (void)n_in; (void)out_size; (void)ws_size;
  const int*   src   = (const int*)d_in[0];
  const int*   trg   = (const int*)d_in[1];
  const float* embed = (const float*)d_in[2];
  const float* eWihF = (const float*)d_in[3];
  const float* eWhhF = (const float*)d_in[4];
  const float* ebihF = (const float*)d_in[5];
  const float* ebhhF = (const float*)d_in[6];
  const float* eWihB = (const float*)d_in[7];
  const float* eWhhB = (const float*)d_in[8];
  const float* ebihB = (const float*)d_in[9];
  const float* ebhhB = (const float*)d_in[10];
  const float* attnW = (const float*)d_in[11];
  const float* attnB = (const float*)d_in[12];
  const float* attnV = (const float*)d_in[13];
  const float* dWih0 = (const float*)d_in[14];
  const float* dWhh0 = (const float*)d_in[15];
  const float* dbih0 = (const float*)d_in[16];
  const float* dbhh0 = (const float*)d_in[17];
  const float* dWih1 = (const float*)d_in[18];
  const float* dWhh1 = (const float*)d_in[19];
  const float* dbih1 = (const float*)d_in[20];
  const float* dbhh1 = (const float*)d_in[21];
  const float* outW  = (const float*)d_in[22];
  const float* outB  = (const float*)d_in[23];

  float* out = (float*)d_out;
  // d_out scratch (all dead before final GEMM writes)
  float* enc_in_f = out;                         // [128][2048][32]
  float* enc_in_b = out + 8388608;
  short* enc_proj_bf = (short*)(out + 18874368); // [4096][512] bf16
  unsigned* f_outs = (unsigned*)(out + 20971520); // [128][32][256] f16 pairs
  unsigned* b_outs = (unsigned*)(out + 23068672);
  float* demb     = out + 25165824;              // [32][2048][32]
  short* emb_src_bf = (short*)(out + 27262976);
  short* emb_trg_bf = (short*)(out + 27787264);
  unsigned* enc_sum_bf_u = (unsigned*)(out + 27918336);  // [4096][256] bf16 pairs
  unsigned short* wqh    = (unsigned short*)(out + 28966912);  // [512][512] f16
  unsigned short* whhF_h = (unsigned short*)(out + 29229056);  // each [2048][512] f16
  unsigned short* whhB_h = (unsigned short*)(out + 29753344);
  unsigned short* wih0_h = (unsigned short*)(out + 30277632);
  unsigned short* whh0_h = (unsigned short*)(out + 30801920);
  unsigned short* wih1_h = (unsigned short*)(out + 31326208);
  unsigned short* whh1_h = (unsigned short*)(out + 31850496);

  char* ws = (char*)d_ws;
  short* h1ctx = (short*)ws;                        // 2 MB
  unsigned* h0buf = (unsigned*)(ws + 2097152);      // [2][32][256]
  unsigned* h1buf = (unsigned*)(ws + 2162688);
  unsigned* ctxb  = (unsigned*)(ws + 2228224);      // [32][256]
  float* c_f      = (float*)(ws + 2260992);         // [32][512]
  float* c_b      = (float*)(ws + 2326528);
  unsigned* eflag = (unsigned*)(ws + 2392064);      // 8*32*16 u
  unsigned* flagC = (unsigned*)(ws + 2408448);      // 4*64*16 u
  unsigned* flagA = (unsigned*)(ws + 2424832);      // 4*8*16 u

  // 1. zero flags (8704 uints)
  k_zero<<<4, 256, 0, stream>>>((float*)eflag, 8704);
  // 2. embedding gathers
  k_gather<<<5120, 256, 0, stream>>>(src, trg, embed, emb_src_bf, emb_trg_bf);
  // 3. batched input projections (transposed [t][j][b])
  {
    dim3 g1(32,16);
    k_gemm_aw<<<g1,256,0,stream>>>(emb_src_bf,256, eWihF,256, enc_in_f,2048, ebihF,ebhhF, 4096,256, 1, nullptr);
    k_gemm_aw<<<g1,256,0,stream>>>(emb_src_bf,256, eWihB,256, enc_in_b,2048, ebihB,ebhhB, 4096,256, 1, nullptr);
    dim3 g2(8,16);
    k_gemm_aw<<<g2,256,0,stream>>>(emb_trg_bf,256, dWih0,768, demb,2048, dbih0,dbhh0, 1024,256, 1, nullptr);
  }
  // 4. f16 weight conversions
  k_cvt_f16<<<1024,256,0,stream>>>(eWhhF, whhF_h, 1048576);
  k_cvt_f16<<<1024,256,0,stream>>>(eWhhB, whhB_h, 1048576);
  k_cvt_f16_str<<<1024,256,0,stream>>>(dWih0+256, 768, wih0_h, 1048576);
  k_cvt_f16<<<1024,256,0,stream>>>(dWhh0, whh0_h, 1048576);
  k_cvt_f16<<<1024,256,0,stream>>>(dWih1, wih1_h, 1048576);
  k_cvt_f16<<<1024,256,0,stream>>>(dWhh1, whh1_h, 1048576);
  k_cvt_f16_str<<<256,256,0,stream>>>(attnW, 1024, wqh, 262144);
  // 5. persistent encoder
  k_enc_persist<<<256, 256, 0, stream>>>(enc_in_f, enc_in_b, whhF_h, whhB_h,
                                         f_outs, b_outs, c_f, c_b, eflag);
  // 6. sum directions -> bf16 pairs
  k_sum_enc<<<4096, 256, 0, stream>>>(f_outs, b_outs, enc_sum_bf_u);
  // 7. attention enc projection (+attn_b), bf16 out
  {
    dim3 g3(32,4);
    k_gemm_aw<<<g3,256,0,stream>>>((const short*)enc_sum_bf_u,512, attnW+512,1024, nullptr,512, attnB,nullptr, 4096,512, 0, enc_proj_bf);
  }
  // 8. persistent decoder
  k_dec_persist<<<256, 256, 0, stream>>>(demb, wih0_h, whh0_h, wih1_h, whh1_h,
                                         dbih1, dbhh1, wqh, attnV, enc_proj_bf,
                                         (const short*)enc_sum_bf_u,
                                         f_outs + (size_t)127*8192, b_outs + (size_t)127*8192,
                                         c_f, c_b, h0buf, h1buf, ctxb, h1ctx, flagC, flagA);
  // 9. outputs[0] = 0
  k_zero<<<512, 256, 0, stream>>>(out, 1024000);
  // 10. batched output projection
  {
    dim3 g4(8,250);
    k_gemm_aw<<<g4,256,0,stream>>>(h1ctx,1024, outW,1024, out + 1024000, 32000, outB,nullptr, 992,1024, 0, nullptr);
  }
  // 11. log_softmax
  k_logsm<<<992, 256, 0, stream>>>(out + 1024000);
}

// Round 9
// 2409.922 us; speedup vs baseline: 1.1223x; 1.1223x over previous
//
#include <hip/hip_runtime.h>
#include <stdint.h>

// V=32000, E=256, H=512, S=128, B=32, T=32

using short8 = __attribute__((ext_vector_type(8))) short;
using f32x4  = __attribute__((ext_vector_type(4))) float;
typedef _Float16 half2v __attribute__((ext_vector_type(2)));

__device__ __forceinline__ short f2bf(float x){
  unsigned u = __float_as_uint(x);
  unsigned r = (u + 0x7fffu + ((u >> 16) & 1u)) >> 16;
  return (short)(unsigned short)r;
}
__device__ __forceinline__ float bf2f_lo(unsigned u){ return __uint_as_float(u << 16); }
__device__ __forceinline__ float bf2f_hi(unsigned u){ return __uint_as_float(u & 0xffff0000u); }
__device__ __forceinline__ float sigmf(float x){ return 1.0f/(1.0f + __expf(-x)); }
__device__ __forceinline__ float fast_tanh(float x){
  const float e = __expf(2.0f*x);
  return 1.0f - 2.0f/(e + 1.0f);
}
__device__ __forceinline__ unsigned pack_h2(float a, float b){
  unsigned short ha = __builtin_bit_cast(unsigned short, (_Float16)a);
  unsigned short hb = __builtin_bit_cast(unsigned short, (_Float16)b);
  return (unsigned)ha | ((unsigned)hb << 16);
}
__device__ __forceinline__ float h2lo(unsigned u){ return (float)__builtin_bit_cast(half2v,u)[0]; }
__device__ __forceinline__ float h2hi(unsigned u){ return (float)__builtin_bit_cast(half2v,u)[1]; }
__device__ __forceinline__ float dot2u(unsigned x, unsigned w, float c){
#if __has_builtin(__builtin_amdgcn_fdot2)
  return __builtin_amdgcn_fdot2(__builtin_bit_cast(half2v,x), __builtin_bit_cast(half2v,w), c, false);
#else
  half2v hx = __builtin_bit_cast(half2v,x), hw = __builtin_bit_cast(half2v,w);
  c = fmaf((float)hx[0], (float)hw[0], c);
  c = fmaf((float)hx[1], (float)hw[1], c);
  return c;
#endif
}

// ---------------------------------------------------------------------------
// coherent (LLC) accessors
__device__ __forceinline__ float4 load_coh_f4(const float* p){
  float4 v;
  asm volatile("global_load_dwordx4 %0, %1, off sc0 sc1\n\ts_waitcnt vmcnt(0)"
               : "=&v"(v) : "v"(p) : "memory");
  return v;
}
__device__ __forceinline__ uint4 load_coh_u4(const unsigned* p){
  uint4 v;
  asm volatile("global_load_dwordx4 %0, %1, off sc0 sc1\n\ts_waitcnt vmcnt(0)"
               : "=&v"(v) : "v"(p) : "memory");
  return v;
}
__device__ __forceinline__ void store_coh_u32(unsigned* p, unsigned v){
  asm volatile("global_store_dword %0, %1, off sc0 sc1" :: "v"(p), "v"(v) : "memory");
}
__device__ __forceinline__ void store_coh_f32(float* p, float v){
  asm volatile("global_store_dword %0, %1, off sc0 sc1" :: "v"(p), "v"(v) : "memory");
}

// spread flags: one flag per 64B line (16 uints). wave0: lane l polls flag l.
__device__ __forceinline__ void wait_spread(const unsigned* base, int n, unsigned target){
  if (threadIdx.x < 64){
    const bool mine = (int)threadIdx.x < n;
    const unsigned* p = base + (threadIdx.x << 4);
    for(;;){
      unsigned v = target;
      if (mine)
        asm volatile("global_load_dword %0, %1, off sc0 sc1\n\ts_waitcnt vmcnt(0)"
                     : "=&v"(v) : "v"(p) : "memory");
      if (__all(v >= target)) break;
    }
  }
  __syncthreads();
}
__device__ __forceinline__ void set_flag_sp(unsigned* slot, unsigned val){
  asm volatile("s_waitcnt vmcnt(0)" ::: "memory");
  __syncthreads();
  if (threadIdx.x == 0) store_coh_u32(slot, val);
}

// stage 8 rows x 256 uints (f16 pairs) from [32][256] (rows bg8*8..+8), LDS stride 260
__device__ __forceinline__ void stage8u(const unsigned* src, int bg8, unsigned* lds){
  const unsigned* s0 = src + (size_t)bg8*2048;
  const int f0 = threadIdx.x, f1 = f0 + 256;
  uint4 a, b;
  asm volatile(
    "global_load_dwordx4 %0, %2, off sc0 sc1\n\t"
    "global_load_dwordx4 %1, %3, off sc0 sc1\n\t"
    "s_waitcnt vmcnt(0)"
    : "=&v"(a), "=&v"(b)
    : "v"(s0 + (f0<<2)), "v"(s0 + (f1<<2))
    : "memory");
  { const int row = f0>>6, cu = (f0&63)<<2; *(uint4*)&lds[row*260+cu] = a; }
  { const int row = f1>>6, cu = (f1&63)<<2; *(uint4*)&lds[row*260+cu] = b; }
}

// stage 4 rows x 256 uints from [32][256] (rows bg4*4..+4), LDS stride 260
__device__ __forceinline__ void stage4u(const unsigned* src, int bg4, unsigned* lds){
  const unsigned* s0 = src + (size_t)bg4*1024;
  uint4 a;
  asm volatile(
    "global_load_dwordx4 %0, %1, off sc0 sc1\n\ts_waitcnt vmcnt(0)"
    : "=&v"(a) : "v"(s0 + (threadIdx.x<<2)) : "memory");
  const int row = threadIdx.x>>6, cu = (threadIdx.x&63)<<2;
  *(uint4*)&lds[row*260+cu] = a;
}

// 512-elem f16 dot
__device__ __forceinline__ float dot512(const unsigned* xrow, const unsigned* w){
  float a = 0.f;
  #pragma unroll 4
  for (int it = 0; it < 16; ++it){
    uint4 x0 = *(const uint4*)(xrow + it*16);
    uint4 x1 = *(const uint4*)(xrow + it*16 + 4);
    uint4 x2 = *(const uint4*)(xrow + it*16 + 8);
    uint4 x3 = *(const uint4*)(xrow + it*16 + 12);
    uint4 w0 = *(const uint4*)(w + it*16);
    uint4 w1 = *(const uint4*)(w + it*16 + 4);
    uint4 w2 = *(const uint4*)(w + it*16 + 8);
    uint4 w3 = *(const uint4*)(w + it*16 + 12);
    a = dot2u(x0.x,w0.x,a); a = dot2u(x0.y,w0.y,a); a = dot2u(x0.z,w0.z,a); a = dot2u(x0.w,w0.w,a);
    a = dot2u(x1.x,w1.x,a); a = dot2u(x1.y,w1.y,a); a = dot2u(x1.z,w1.z,a); a = dot2u(x1.w,w1.w,a);
    a = dot2u(x2.x,w2.x,a); a = dot2u(x2.y,w2.y,a); a = dot2u(x2.z,w2.z,a); a = dot2u(x2.w,w2.w,a);
    a = dot2u(x3.x,w3.x,a); a = dot2u(x3.y,w3.y,a); a = dot2u(x3.z,w3.z,a); a = dot2u(x3.w,w3.w,a);
  }
  return a;
}

// two weight rows vs same LDS x
__device__ __forceinline__ float2 dot2rows(const unsigned* xrow, const unsigned* wA, const unsigned* wB){
  float a = 0.f, b = 0.f;
  #pragma unroll 8
  for (int it = 0; it < 32; ++it){
    uint4 x0 = *(const uint4*)(xrow + it*8);
    uint4 x1 = *(const uint4*)(xrow + it*8 + 4);
    uint4 a0 = *(const uint4*)(wA + it*8);
    uint4 a1 = *(const uint4*)(wA + it*8 + 4);
    uint4 b0 = *(const uint4*)(wB + it*8);
    uint4 b1 = *(const uint4*)(wB + it*8 + 4);
    a = dot2u(x0.x,a0.x,a); a = dot2u(x0.y,a0.y,a); a = dot2u(x0.z,a0.z,a); a = dot2u(x0.w,a0.w,a);
    a = dot2u(x1.x,a1.x,a); a = dot2u(x1.y,a1.y,a); a = dot2u(x1.z,a1.z,a); a = dot2u(x1.w,a1.w,a);
    b = dot2u(x0.x,b0.x,b); b = dot2u(x0.y,b0.y,b); b = dot2u(x0.z,b0.z,b); b = dot2u(x0.w,b0.w,b);
    b = dot2u(x1.x,b1.x,b); b = dot2u(x1.y,b1.y,b); b = dot2u(x1.z,b1.z,b); b = dot2u(x1.w,b1.w,b);
  }
  return make_float2(a, b);
}

// ---------------------------------------------------------------------------
__global__ void k_zero(float* __restrict__ p, int n){
  int i = blockIdx.x*256 + threadIdx.x;
  const int stride = gridDim.x*256;
  for (; i < n; i += stride) p[i] = 0.f;
}

__global__ __launch_bounds__(256) void k_cvt_f16(const float* __restrict__ s, unsigned short* __restrict__ d, int n){
  int i = blockIdx.x*256 + threadIdx.x;
  const int stride = gridDim.x*256;
  for (; i < n; i += stride) d[i] = __builtin_bit_cast(unsigned short, (_Float16)s[i]);
}
__global__ __launch_bounds__(256) void k_cvt_f16_str(const float* __restrict__ s, int lds_, unsigned short* __restrict__ d, int n){
  int i = blockIdx.x*256 + threadIdx.x;
  const int stride = gridDim.x*256;
  for (; i < n; i += stride){
    const int row = i >> 9, c = i & 511;
    d[i] = __builtin_bit_cast(unsigned short, (_Float16)s[(size_t)row*lds_ + c]);
  }
}

// ---------------------------------------------------------------------------
__global__ __launch_bounds__(256) void k_gather(
    const int* __restrict__ src, const int* __restrict__ trg,
    const float* __restrict__ embed,
    short* __restrict__ emb_src_bf, short* __restrict__ emb_trg_bf)
{
  const int row = blockIdx.x, tid = threadIdx.x;
  if (row < 4096){
    const int tok = src[row];
    emb_src_bf[(size_t)row*256 + tid] = f2bf(embed[(size_t)tok*256 + tid]);
  } else {
    const int r = row - 4096;
    short v = 0;
    if (r < 992){ const int tok = trg[r]; v = f2bf(embed[(size_t)tok*256 + tid]); }
    emb_trg_bf[(size_t)r*256 + tid] = v;
  }
}

// ---------------------------------------------------------------------------
// MFMA GEMM: A_bf16 @ W_f32^T + biases. tmode: C_T[t][col][b]; Cbf: bf16 output
__global__ __launch_bounds__(256) void k_gemm_aw(
    const short* __restrict__ A, int lda,
    const float* __restrict__ W, int ldw,
    float* __restrict__ C, int ldc,
    const float* __restrict__ bias0, const float* __restrict__ bias1,
    int Mvalid, int K, int tmode, short* __restrict__ Cbf)
{
  __shared__ __align__(16) short As[128*32];
  __shared__ __align__(16) short Bs[128*32];
  const int tid = threadIdx.x;
  const int bm = blockIdx.x, bn = blockIdx.y;
  const int w  = tid >> 6,  l  = tid & 63;
  const int wm = w >> 1,    wn = w & 1;
  const int lr = l & 15,    lk = l >> 4;

  const int r0 = tid >> 2;
  const int s0 = (tid & 3) << 3;
  const int r1 = r0 + 64;

  const short* a0 = A + (size_t)(bm*128 + r0)*lda + s0;
  const short* a1 = A + (size_t)(bm*128 + r1)*lda + s0;
  const float* w0 = W + (size_t)(bn*128 + r0)*ldw + s0;
  const float* w1 = W + (size_t)(bn*128 + r1)*ldw + s0;

  const f32x4 zero4 = {0.f,0.f,0.f,0.f};
  f32x4 acc[4][4];
  #pragma unroll
  for (int mi=0;mi<4;mi++){
    #pragma unroll
    for (int ni=0;ni<4;ni++) acc[mi][ni] = zero4;
  }

  for (int k0 = 0; k0 < K; k0 += 32){
    short8 va0 = *(const short8*)(a0 + k0);
    short8 va1 = *(const short8*)(a1 + k0);
    float4 f00 = *(const float4*)(w0 + k0);
    float4 f01 = *(const float4*)(w0 + k0 + 4);
    float4 f10 = *(const float4*)(w1 + k0);
    float4 f11 = *(const float4*)(w1 + k0 + 4);
    short8 vb0, vb1;
    vb0[0]=f2bf(f00.x); vb0[1]=f2bf(f00.y); vb0[2]=f2bf(f00.z); vb0[3]=f2bf(f00.w);
    vb0[4]=f2bf(f01.x); vb0[5]=f2bf(f01.y); vb0[6]=f2bf(f01.z); vb0[7]=f2bf(f01.w);
    vb1[0]=f2bf(f10.x); vb1[1]=f2bf(f10.y); vb1[2]=f2bf(f10.z); vb1[3]=f2bf(f10.w);
    vb1[4]=f2bf(f11.x); vb1[5]=f2bf(f11.y); vb1[6]=f2bf(f11.z); vb1[7]=f2bf(f11.w);

    __syncthreads();
    *((short8*)As + tid)       = va0;
    *((short8*)As + tid + 256) = va1;
    *((short8*)Bs + tid)       = vb0;
    *((short8*)Bs + tid + 256) = vb1;
    __syncthreads();

    short8 af[4], bfr[4];
    #pragma unroll
    for (int mi=0;mi<4;mi++) af[mi]  = *(const short8*)&As[(wm*64 + mi*16 + lr)*32 + (lk<<3)];
    #pragma unroll
    for (int ni=0;ni<4;ni++) bfr[ni] = *(const short8*)&Bs[(wn*64 + ni*16 + lr)*32 + (lk<<3)];
    #pragma unroll
    for (int mi=0;mi<4;mi++){
      #pragma unroll
      for (int ni=0;ni<4;ni++)
        acc[mi][ni] = __builtin_amdgcn_mfma_f32_16x16x32_bf16(af[mi], bfr[ni], acc[mi][ni], 0,0,0);
    }
  }

  #pragma unroll
  for (int mi=0;mi<4;mi++){
    const int rb = bm*128 + wm*64 + mi*16 + (lk<<2);
    #pragma unroll
    for (int ni=0;ni<4;ni++){
      const int col = bn*128 + wn*64 + ni*16 + lr;
      float bv = 0.f;
      if (bias0) bv += bias0[col];
      if (bias1) bv += bias1[col];
      #pragma unroll
      for (int rr=0;rr<4;rr++){
        const int row = rb + rr;
        if (row < Mvalid){
          const float vv = acc[mi][ni][rr] + bv;
          if (Cbf)        Cbf[(size_t)row*ldc + col] = f2bf(vv);
          else if (tmode) C[(size_t)(row>>5)*65536 + (size_t)col*32 + (row&31)] = vv;
          else            C[(size_t)row*ldc + col] = vv;
        }
      }
    }
  }
}

// ---------------------------------------------------------------------------
// persistent bidirectional encoder, 256 blocks (unchanged from r8).
__global__ __launch_bounds__(256,1) void k_enc_persist(
    const float* __restrict__ pre_f, const float* __restrict__ pre_b,
    const unsigned short* __restrict__ WhF, const unsigned short* __restrict__ WhB,
    unsigned* __restrict__ f_outs, unsigned* __restrict__ b_outs,      // [128][32][256]
    float* __restrict__ c_f_out, float* __restrict__ c_b_out,
    unsigned* __restrict__ eflag)
{
  __shared__ __align__(16) unsigned x_lds[8*260];
  __shared__ float zbuf[64*8];
  const int bid = blockIdx.x, tid = threadIdx.x;
  const int x = bid & 7, m = bid >> 3;
  const int dir = m & 1, bg = (m >> 1) & 3, q = m >> 3;
  const int jb = x*4 + q;
  const float* pre = dir ? pre_b : pre_f;
  const unsigned* Wh = (const unsigned*)(dir ? WhB : WhF);
  unsigned* outs = dir ? b_outs : f_outs;
  float* c_out = dir ? c_b_out : c_f_out;
  unsigned* flags = eflag + (size_t)(dir*4 + bg)*512;

  const int bb = tid & 7, rr = tid >> 3;
  const int g = rr >> 3, op = rr & 7;
  const unsigned* wA = Wh + (size_t)(g*512 + jb*16 + 2*op)*256;
  const unsigned* wB = wA + 256;

  const int fo = tid & 15, fb = tid >> 4;
  const int b_out = bg*8 + fb, k_out = jb*16 + fo;
  float c_reg = 0.f;

  for (int t = 0; t < 128; ++t){
    float pz[4];
    if (tid < 128){
      const int tt = dir ? (127 - t) : t;
      const float* pt = pre + (size_t)tt*65536;
      #pragma unroll
      for (int gg = 0; gg < 4; ++gg)
        pz[gg] = pt[(size_t)(gg*512 + k_out)*32 + b_out];
    }
    if (t){
      wait_spread(flags, 32, (unsigned)t);
      stage8u(outs + (size_t)(t-1)*8192, bg, x_lds);
    } else {
      for (int i = tid; i < 8*260; i += 256) x_lds[i] = 0;
    }
    __syncthreads();

    const float2 d = dot2rows(x_lds + bb*260, wA, wB);
    zbuf[(g*16 + 2*op)*8 + bb]   = d.x;
    zbuf[(g*16 + 2*op+1)*8 + bb] = d.y;
    __syncthreads();

    if (tid < 128){
      float z[4];
      #pragma unroll
      for (int gg = 0; gg < 4; ++gg)
        z[gg] = pz[gg] + zbuf[(gg*16 + fo)*8 + fb];
      const float cn = sigmf(z[1])*c_reg + sigmf(z[0])*fast_tanh(z[2]);
      c_reg = cn;
      const float hn = sigmf(z[3])*fast_tanh(cn);
      const unsigned pu = pack_h2(hn, __shfl_xor(hn, 1));
      if (!(tid & 1))
        store_coh_u32(outs + (size_t)t*8192 + (size_t)b_out*256 + (k_out>>1), pu);
    }
    set_flag_sp(flags + jb*16, (unsigned)(t+1));
  }
  if (tid < 128) c_out[b_out*512 + k_out] = c_reg;
}

// ---------------------------------------------------------------------------
__global__ __launch_bounds__(256) void k_sum_enc(
    const unsigned* __restrict__ f_o, const unsigned* __restrict__ b_o,
    unsigned* __restrict__ enc_sum_bf_u)
{
  const int i = blockIdx.x*256 + threadIdx.x;
  const int s = i >> 13, rem = i & 8191;
  const unsigned a = f_o[i], b = b_o[(size_t)(127 - s)*8192 + rem];
  const float lo = h2lo(a) + h2lo(b);
  const float hi = h2hi(a) + h2hi(b);
  enc_sum_bf_u[i] = (unsigned)(unsigned short)f2bf(lo) | ((unsigned)(unsigned short)f2bf(hi) << 16);
}

// ---------------------------------------------------------------------------
// persistent decoder, 256 blocks. 8 independent batch-group domains (4 rows each)
// x=bid&7, m=bid>>3: bg=m&7, q=m>>3, jb=x*4+q (0..31; 16 j-cols per block).
// Same-jb blocks share an XCD -> L2-resident weight slice (~1.1 MB/XCD).
// Phases: P1 {stage h1, zh1, distributed qs} -> P2 {attn on jb%8==0 blocks}
//         -> P3 {cell0} -> P4 {cell1 + zh0'}
__global__ __launch_bounds__(256,1) void k_dec_persist(
    const float* __restrict__ demb,               // [32][2048][32] (+bih0+bhh0)
    const unsigned short* __restrict__ Wih0h,
    const unsigned short* __restrict__ Whh0h,
    const unsigned short* __restrict__ Wih1h,
    const unsigned short* __restrict__ Whh1h,
    const float* __restrict__ bih1, const float* __restrict__ bhh1,
    const unsigned short* __restrict__ wqh,       // f16 [512][512]
    const float* __restrict__ attnV,
    const short* __restrict__ enc_proj_bf,        // [4096][512] (+attn_b)
    const unsigned* __restrict__ enc_sum_u,       // [4096][256] bf16 pairs
    const unsigned* __restrict__ h0i, const unsigned* __restrict__ h1i, // [32][256]
    const float* __restrict__ c0_init, const float* __restrict__ c1_init,
    unsigned* __restrict__ h0buf, unsigned* __restrict__ h1buf,  // [2][32][256]
    unsigned* __restrict__ ctxb,                                 // [32][256]
    float* __restrict__ qsb,                                     // [32][512] f32
    short* __restrict__ h1ctx,                                   // [31][32][1024]
    unsigned* __restrict__ flagQ, unsigned* __restrict__ flagH0,
    unsigned* __restrict__ flagH1, unsigned* __restrict__ flagCtx)
{
  __shared__ __align__(16) unsigned x1s[4*260];
  __shared__ __align__(16) unsigned x0s[4*260];
  __shared__ float zfin[64*5];
  __shared__ __align__(16) float q_s[512], v_s[512];
  __shared__ float part[256], aw[128], red[128];

  const int bid = blockIdx.x, tid = threadIdx.x;
  const int x = bid & 7, m = bid >> 3;
  const int bg = m & 7, q = m >> 3;
  const int jb = x*4 + q;                    // 0..31
  const bool is_attn = ((jb & 7) == 0);
  const int ar = jb >> 3;                    // 0..3 (attn row within bg)
  const int ab = bg*4 + ar;                  // batch row for attn

  unsigned* fQ  = flagQ  + bg*512;
  unsigned* fH0 = flagH0 + bg*512;
  unsigned* fH1 = flagH1 + bg*512;
  unsigned* fCt = flagCtx + bg*64;

  const int b  = tid & 3;                    // batch-local row 0..3
  const int jr = tid >> 2;                   // 0..63
  const int g  = jr >> 4, col = jr & 15;
  const int j_row = g*512 + jb*16 + col;

  const int fcol = tid & 15, fb2 = tid >> 4; // finish (tid<64): fb2 0..3
  const int b_out = bg*4 + fb2, k_out = jb*16 + fcol;

  const unsigned* Wh0row = (const unsigned*)Whh0h + (size_t)j_row*256;
  const unsigned* Wh1row = (const unsigned*)Whh1h + (size_t)j_row*256;
  const unsigned* Wi0row = (const unsigned*)Wih0h + (size_t)j_row*256;
  const unsigned* Wi1row = (const unsigned*)Wih1h + (size_t)j_row*256;
  const unsigned* WQu    = (const unsigned*)wqh;

  float c0_reg = 0.f, c1_reg = 0.f, bias1g[4];
  if (tid < 64){
    c0_reg = c0_init[b_out*512 + k_out];
    c1_reg = c1_init[b_out*512 + k_out];
    #pragma unroll
    for (int gg=0; gg<4; ++gg) bias1g[gg] = bih1[gg*512 + k_out] + bhh1[gg*512 + k_out];
  }
  if (is_attn && tid < 128) ((float4*)v_s)[tid] = ((const float4*)attnV)[tid];

  float zh0 = 0.f;

  for (int t = 0; t < 31; ++t){
    const float demb_v = demb[(size_t)t*65536 + (size_t)j_row*32 + bg*4 + b];

    // ---------------- P1: stage h1[t-1]; zh1; distributed qs ----------------
    if (t){
      wait_spread(fH1, 32, (unsigned)t);
      stage4u(h1buf + (size_t)(t&1)*8192, bg, x1s);
    } else {
      stage4u(h1i, bg, x1s);
      stage4u(h0i, bg, x0s);
    }
    __syncthreads();
    if (t == 0) zh0 = dot512(x0s + b*260, Wh0row);
    const float zh1 = dot512(x1s + b*260, Wh1row);
    if (tid < 64){
      const int qb = tid >> 4, qcol = jb*16 + (tid & 15);
      const float qv = dot512(x1s + qb*260, WQu + (size_t)qcol*256);
      store_coh_f32(qsb + (size_t)(bg*4 + qb)*512 + qcol, qv);
    }
    set_flag_sp(fQ + jb*16, (unsigned)(t+1));

    // ---------------- P2: attention (jb%8==0 blocks) ----------------
    if (is_attn){
      wait_spread(fQ, 32, (unsigned)(t+1));
      if (tid < 128) ((float4*)q_s)[tid] = load_coh_f4(qsb + (size_t)ab*512 + (tid<<2));
      __syncthreads();
      {
        const int s = tid >> 1, half = tid & 1;
        const unsigned* ep = (const unsigned*)(enc_proj_bf + ((size_t)(s*32 + ab))*512 + (half << 8));
        const float* qh = q_s + (half << 8);
        const float* vh = v_s + (half << 8);
        float p = 0.f;
        for (int kk = 0; kk < 128; kk += 4){
          uint4 e = *(const uint4*)(ep + kk);
          const int k2 = kk << 1;
          p += fast_tanh(qh[k2+0] + bf2f_lo(e.x)) * vh[k2+0];
          p += fast_tanh(qh[k2+1] + bf2f_hi(e.x)) * vh[k2+1];
          p += fast_tanh(qh[k2+2] + bf2f_lo(e.y)) * vh[k2+2];
          p += fast_tanh(qh[k2+3] + bf2f_hi(e.y)) * vh[k2+3];
          p += fast_tanh(qh[k2+4] + bf2f_lo(e.z)) * vh[k2+4];
          p += fast_tanh(qh[k2+5] + bf2f_hi(e.z)) * vh[k2+5];
          p += fast_tanh(qh[k2+6] + bf2f_lo(e.w)) * vh[k2+6];
          p += fast_tanh(qh[k2+7] + bf2f_hi(e.w)) * vh[k2+7];
        }
        part[tid] = p;
      }
      __syncthreads();
      if (tid < 128){ const float sc = part[2*tid] + part[2*tid+1]; aw[tid] = sc; red[tid] = sc; }
      __syncthreads();
      for (int off = 64; off > 0; off >>= 1){
        if (tid < off) red[tid] = fmaxf(red[tid], red[tid+off]);
        __syncthreads();
      }
      const float mx = red[0];
      __syncthreads();
      if (tid < 128){ const float e = __expf(aw[tid] - mx); aw[tid] = e; red[tid] = e; }
      __syncthreads();
      for (int off = 64; off > 0; off >>= 1){
        if (tid < off) red[tid] += red[tid+off];
        __syncthreads();
      }
      const float inv = 1.0f / red[0];
      if (tid < 128) aw[tid] *= inv;
      __syncthreads();
      {
        const int cc = tid << 1;
        float x0 = 0.f, x1 = 0.f;
        for (int s2 = 0; s2 < 128; ++s2){
          const unsigned u = enc_sum_u[(size_t)(s2*32 + ab)*256 + tid];
          const float a = aw[s2];
          x0 = fmaf(a, bf2f_lo(u), x0);
          x1 = fmaf(a, bf2f_hi(u), x1);
        }
        store_coh_u32(ctxb + (size_t)ab*256 + tid, pack_h2(x0, x1));
        h1ctx[(size_t)t*32768 + ab*1024 + 512 + cc]     = f2bf(x0);
        h1ctx[(size_t)t*32768 + ab*1024 + 512 + cc + 1] = f2bf(x1);
      }
      set_flag_sp(fCt + ar*16, (unsigned)(t+1));
    }

    // ---------------- P3: cell0 ----------------
    wait_spread(fCt, 4, (unsigned)(t+1));
    stage4u(ctxb, bg, x0s);
    __syncthreads();
    zfin[jr*5 + b] = demb_v + dot512(x0s + b*260, Wi0row) + zh0;
    __syncthreads();
    if (tid < 64){
      float z[4];
      #pragma unroll
      for (int gg=0; gg<4; ++gg) z[gg] = zfin[(gg*16 + fcol)*5 + fb2];
      const float cn = sigmf(z[1])*c0_reg + sigmf(z[0])*fast_tanh(z[2]);
      c0_reg = cn;
      const float hn = sigmf(z[3])*fast_tanh(cn);
      const unsigned pu = pack_h2(hn, __shfl_xor(hn, 1));
      if (!(tid & 1))
        store_coh_u32(h0buf + (size_t)((t+1)&1)*8192 + (size_t)b_out*256 + (k_out>>1), pu);
    }
    set_flag_sp(fH0 + jb*16, (unsigned)(t+1));

    // ---------------- P4: cell1 + zh0' ----------------
    wait_spread(fH0, 32, (unsigned)(t+1));
    stage4u(h0buf + (size_t)((t+1)&1)*8192, bg, x1s);
    __syncthreads();
    {
      const float2 d = dot2rows(x1s + b*260, Wi1row, Wh0row);
      zfin[jr*5 + b] = d.x + zh1;
      zh0 = d.y;
    }
    __syncthreads();
    if (tid < 64){
      float z[4];
      #pragma unroll
      for (int gg=0; gg<4; ++gg) z[gg] = bias1g[gg] + zfin[(gg*16 + fcol)*5 + fb2];
      const float cn = sigmf(z[1])*c1_reg + sigmf(z[0])*fast_tanh(z[2]);
      c1_reg = cn;
      const float hn = sigmf(z[3])*fast_tanh(cn);
      const unsigned pu = pack_h2(hn, __shfl_xor(hn, 1));
      if (!(tid & 1))
        store_coh_u32(h1buf + (size_t)((t+1)&1)*8192 + (size_t)b_out*256 + (k_out>>1), pu);
      h1ctx[(size_t)t*32768 + (size_t)b_out*1024 + k_out] = f2bf(hn);
    }
    set_flag_sp(fH1 + jb*16, (unsigned)(t+1));
  }
}

// ---------------------------------------------------------------------------
__global__ __launch_bounds__(256) void k_logsm(float* __restrict__ out){
  float* row = out + (size_t)blockIdx.x * 32000;
  const int tid = threadIdx.x;
  __shared__ float red[256];
  float s = 0.f;
  for (int i = tid; i < 8000; i += 256){
    const float4 v = ((const float4*)row)[i];
    s += __expf(v.x) + __expf(v.y) + __expf(v.z) + __expf(v.w);
  }
  red[tid] = s; __syncthreads();
  for (int off = 128; off > 0; off >>= 1){
    if (tid < off) red[tid] += red[tid+off];
    __syncthreads();
  }
  const float lse = __logf(red[0]);
  for (int i = tid; i < 8000; i += 256){
    float4 v = ((const float4*)row)[i];
    v.x -= lse; v.y -= lse; v.z -= lse; v.w -= lse;
    ((float4*)row)[i] = v;
  }
}

// ---------------------------------------------------------------------------
extern "C" void kernel_launch(void* const* d_in, const int* in_sizes, int n_in,
                              void* d_out, int out_size, void* d_ws, size_t ws_size,
                              hipStream_t stream)
{
  (void)in_sizes; (void)n_in; (void)out_size; (void)ws_size;
  const int*   src   = (const int*)d_in[0];
  const int*   trg   = (const int*)d_in[1];
  const float* embed = (const float*)d_in[2];
  const float* eWihF = (const float*)d_in[3];
  const float* eWhhF = (const float*)d_in[4];
  const float* ebihF = (const float*)d_in[5];
  const float* ebhhF = (const float*)d_in[6];
  const float* eWihB = (const float*)d_in[7];
  const float* eWhhB = (const float*)d_in[8];
  const float* ebihB = (const float*)d_in[9];
  const float* ebhhB = (const float*)d_in[10];
  const float* attnW = (const float*)d_in[11];
  const float* attnB = (const float*)d_in[12];
  const float* attnV = (const float*)d_in[13];
  const float* dWih0 = (const float*)d_in[14];
  const float* dWhh0 = (const float*)d_in[15];
  const float* dbih0 = (const float*)d_in[16];
  const float* dbhh0 = (const float*)d_in[17];
  const float* dWih1 = (const float*)d_in[18];
  const float* dWhh1 = (const float*)d_in[19];
  const float* dbih1 = (const float*)d_in[20];
  const float* dbhh1 = (const float*)d_in[21];
  const float* outW  = (const float*)d_in[22];
  const float* outB  = (const float*)d_in[23];

  float* out = (float*)d_out;
  float* enc_in_f = out;                         // [128][2048][32]
  float* enc_in_b = out + 8388608;
  short* enc_proj_bf = (short*)(out + 18874368); // [4096][512] bf16
  unsigned* f_outs = (unsigned*)(out + 20971520); // [128][32][256] f16 pairs
  unsigned* b_outs = (unsigned*)(out + 23068672);
  float* demb     = out + 25165824;              // [32][2048][32]
  short* emb_src_bf = (short*)(out + 27262976);
  short* emb_trg_bf = (short*)(out + 27787264);
  unsigned* enc_sum_bf_u = (unsigned*)(out + 27918336);  // [4096][256]
  unsigned short* wqh    = (unsigned short*)(out + 28966912);
  unsigned short* whhF_h = (unsigned short*)(out + 29229056);
  unsigned short* whhB_h = (unsigned short*)(out + 29753344);
  unsigned short* wih0_h = (unsigned short*)(out + 30277632);
  unsigned short* whh0_h = (unsigned short*)(out + 30801920);
  unsigned short* wih1_h = (unsigned short*)(out + 31326208);
  unsigned short* whh1_h = (unsigned short*)(out + 31850496);
  float* qsb            = out + 32374784;        // [32][512] f32

  char* ws = (char*)d_ws;
  short* h1ctx = (short*)ws;                        // 2 MB
  unsigned* h0buf = (unsigned*)(ws + 2097152);      // [2][32][256]
  unsigned* h1buf = (unsigned*)(ws + 2162688);
  unsigned* ctxb  = (unsigned*)(ws + 2228224);      // [32][256]
  float* c_f      = (float*)(ws + 2260992);         // [32][512]
  float* c_b      = (float*)(ws + 2326528);
  unsigned* eflag   = (unsigned*)(ws + 2392064);    // 4096 u
  unsigned* flagQ   = (unsigned*)(ws + 2408448);    // 4096 u
  unsigned* flagH0  = (unsigned*)(ws + 2424832);    // 4096 u
  unsigned* flagH1  = (unsigned*)(ws + 2441216);    // 4096 u
  unsigned* flagCtx = (unsigned*)(ws + 2457600);    // 512 u

  // 1. zero all flags (16896 uints from eflag)
  k_zero<<<8, 256, 0, stream>>>((float*)eflag, 16896);
  // 2. embedding gathers
  k_gather<<<5120, 256, 0, stream>>>(src, trg, embed, emb_src_bf, emb_trg_bf);
  // 3. batched input projections (transposed [t][j][b])
  {
    dim3 g1(32,16);
    k_gemm_aw<<<g1,256,0,stream>>>(emb_src_bf,256, eWihF,256, enc_in_f,2048, ebihF,ebhhF, 4096,256, 1, nullptr);
    k_gemm_aw<<<g1,256,0,stream>>>(emb_src_bf,256, eWihB,256, enc_in_b,2048, ebihB,ebhhB, 4096,256, 1, nullptr);
    dim3 g2(8,16);
    k_gemm_aw<<<g2,256,0,stream>>>(emb_trg_bf,256, dWih0,768, demb,2048, dbih0,dbhh0, 1024,256, 1, nullptr);
  }
  // 4. f16 weight conversions
  k_cvt_f16<<<1024,256,0,stream>>>(eWhhF, whhF_h, 1048576);
  k_cvt_f16<<<1024,256,0,stream>>>(eWhhB, whhB_h, 1048576);
  k_cvt_f16_str<<<1024,256,0,stream>>>(dWih0+256, 768, wih0_h, 1048576);
  k_cvt_f16<<<1024,256,0,stream>>>(dWhh0, whh0_h, 1048576);
  k_cvt_f16<<<1024,256,0,stream>>>(dWih1, wih1_h, 1048576);
  k_cvt_f16<<<1024,256,0,stream>>>(dWhh1, whh1_h, 1048576);
  k_cvt_f16_str<<<256,256,0,stream>>>(attnW, 1024, wqh, 262144);
  // 5. persistent encoder
  k_enc_persist<<<256, 256, 0, stream>>>(enc_in_f, enc_in_b, whhF_h, whhB_h,
                                         f_outs, b_outs, c_f, c_b, eflag);
  // 6. sum directions -> bf16 pairs
  k_sum_enc<<<4096, 256, 0, stream>>>(f_outs, b_outs, enc_sum_bf_u);
  // 7. attention enc projection (+attn_b), bf16 out
  {
    dim3 g3(32,4);
    k_gemm_aw<<<g3,256,0,stream>>>((const short*)enc_sum_bf_u,512, attnW+512,1024, nullptr,512, attnB,nullptr, 4096,512, 0, enc_proj_bf);
  }
  // 8. persistent decoder
  k_dec_persist<<<256, 256, 0, stream>>>(demb, wih0_h, whh0_h, wih1_h, whh1_h,
                                         dbih1, dbhh1, wqh, attnV, enc_proj_bf,
                                         enc_sum_bf_u,
                                         f_outs + (size_t)127*8192, b_outs + (size_t)127*8192,
                                         c_f, c_b, h0buf, h1buf, ctxb, qsb, h1ctx,
                                         flagQ, flagH0, flagH1, flagCtx);
  // 9. outputs[0] = 0
  k_zero<<<512, 256, 0, stream>>>(out, 1024000);
  // 10. batched output projection
  {
    dim3 g4(8,250);
    k_gemm_aw<<<g4,256,0,stream>>>(h1ctx,1024, outW,1024, out + 1024000, 32000, outB,nullptr, 992,1024, 0, nullptr);
  }
  // 11. log_softmax
  k_logsm<<<992, 256, 0, stream>>>(out + 1024000);
}